// Round 1
// baseline (362.478 us; speedup 1.0000x reference)
//
#include <hip/hip_runtime.h>

// TranslationInvariantMP fused kernel for MI355X (gfx950)
// V=100000 vertices, K=32 neighbours, F=64 features, two dense layers 64->64.
//
// Layout decisions:
//  - one wave (64 lanes) per vertex, lane == feature index
//  - 8 vertices per wave (TPW) to amortize the per-wave weight-register load
//  - weights held in 64 VGPRs per lane (lane j holds W[:,j])
//  - per-vertex w_k / neighbour byte-offsets staged in LDS, consumed as
//    float4/int4 broadcast reads (16 ds_read_b128 per vertex instead of
//    64 ds_bpermute shuffles)

constexpr int VN  = 100000;
constexpr int KN  = 32;
constexpr int FN  = 64;
constexpr int TPW = 8;               // vertices per wave
constexpr int WPB = 4;               // waves per block (256 threads)
constexpr int VPB = TPW * WPB;       // vertices per block = 32

template <bool FIRST, int RBYTES>
__global__ __launch_bounds__(256, 4)
void mp_layer(const float* __restrict__ feat,   // gather source, row stride RBYTES bytes
              const int*   __restrict__ nbidx,  // [V][32] int32
              const float* __restrict__ distsq, // [V][32] f32
              const float* __restrict__ Wmat,   // [64][64] f32 (row f, col j)
              const float* __restrict__ bias,   // [64] or nullptr
              float*       __restrict__ out,    // [V][128] f32
              int out_col)                      // 0 (h0) or 64 (h1)
{
    const int lane = threadIdx.x & 63;
    const int wid  = threadIdx.x >> 6;

    __shared__ float s_w[WPB][KN];
    __shared__ int   s_o[WPB][KN];
    __shared__ float s_agg[WPB][FN];

    // per-lane weight column: lane j holds W[f][j] for all f (64 VGPRs)
    float wreg[FN];
#pragma unroll
    for (int f = 0; f < FN; ++f) wreg[f] = Wmat[f * FN + lane];
    const float breg = bias ? bias[lane] : 0.0f;

    const int vbase = (blockIdx.x * WPB + wid) * TPW;

    for (int t = 0; t < TPW; ++t) {
        const int v = vbase + t;
        if (v >= VN) break;                    // wave-uniform

        // lanes 0..31 compute w_k = exp(-10*d_k) and neighbour byte offsets
        if (lane < KN) {
            float d  = distsq[v * KN + lane];
            float w  = __expf(-10.0f * d);
            int   ix = nbidx[v * KN + lane];
            s_w[wid][lane] = w;
            s_o[wid][lane] = ix * RBYTES;      // max 100000*512 < 2^31
        }
        // same-wave LDS write->read: DS pipe is in-order per wave, compiler
        // inserts the lgkmcnt waits; no __syncthreads needed (per-wid slices).

        float acc  = 0.0f;
        float wsum = 0.0f;
        const char*   fbase = (const char*)feat + (size_t)lane * 4;
        const float4* wv4   = (const float4*)s_w[wid];
        const int4*   ov4   = (const int4*)s_o[wid];
#pragma unroll
        for (int k4 = 0; k4 < KN / 4; ++k4) {
            float4 w4 = wv4[k4];               // broadcast b128
            int4   o4 = ov4[k4];               // broadcast b128
            acc += w4.x * *(const float*)(fbase + o4.x);
            acc += w4.y * *(const float*)(fbase + o4.y);
            acc += w4.z * *(const float*)(fbase + o4.z);
            acc += w4.w * *(const float*)(fbase + o4.w);
            if (FIRST) wsum += (w4.x + w4.y) + (w4.z + w4.w);
        }
        if (FIRST) {
            // translation invariance: subtract x_v * sum_k w_k
            float self = *(const float*)(fbase + (size_t)v * RBYTES);
            acc -= self * wsum;
        }
        acc *= (1.0f / KN);                    // mean semantics (/K)

        // dense: h_j = b_j + sum_f agg_f * W[f][j], j = lane
        s_agg[wid][lane] = acc;
        float h = breg;
        const float4* a4 = (const float4*)s_agg[wid];
#pragma unroll
        for (int f4 = 0; f4 < FN / 4; ++f4) {
            float4 a = a4[f4];                 // broadcast b128
            h += a.x * wreg[4 * f4 + 0];
            h += a.y * wreg[4 * f4 + 1];
            h += a.z * wreg[4 * f4 + 2];
            h += a.w * wreg[4 * f4 + 3];
        }
        // ELU (alpha=1)
        float r = (h > 0.0f) ? h : (__expf(h) - 1.0f);
        out[(size_t)v * 128 + out_col + lane] = r;
    }
}

extern "C" void kernel_launch(void* const* d_in, const int* in_sizes, int n_in,
                              void* d_out, int out_size, void* d_ws, size_t ws_size,
                              hipStream_t stream) {
    const float* x   = (const float*)d_in[0];
    const int*   nb  = (const int*)  d_in[1];
    const float* dsq = (const float*)d_in[2];
    const float* W0  = (const float*)d_in[3];
    const float* W1  = (const float*)d_in[4];
    const float* b1  = (const float*)d_in[5];
    float* out = (float*)d_out;

    const int blocks = (VN + VPB - 1) / VPB;   // 3125

    // layer 0: gather x (rows 256B), translation-invariant, no bias -> out[:,0:64]
    mp_layer<true, 256><<<blocks, 256, 0, stream>>>(x, nb, dsq, W0, nullptr, out, 0);
    // layer 1: gather h0 from out (rows 512B, cols 0..63), +bias -> out[:,64:128]
    mp_layer<false, 512><<<blocks, 256, 0, stream>>>(out, nb, dsq, W1, b1, out, 64);
}

// Round 4
// 358.481 us; speedup vs baseline: 1.0111x; 1.0111x over previous
//
#include <hip/hip_runtime.h>

// TranslationInvariantMP, linearity-split into 4 passes (MI355X/gfx950):
//   A: y0 = x @ W0            (tiny GEMM, 100k x 64 x 64)
//   B: h0 = elu(agg_TI(y0))   (pure gather-agg, translation-invariant term)
//   C: z  = h0 @ W1           (tiny GEMM)
//   D: h1 = elu(agg(z) + b1)  (pure gather-agg)
// Valid because aggregation is linear: agg(x)@W = agg(x@W).
//
// Gather kernel: lane = (tq = vertex-in-quad, fq = float4 slice of 64 feats).
// One wave handles 8 vertices; each gather instruction is global_load_dwordx4
// covering 4 vertices' neighbour rows (4 x 256B segments). No cross-lane
// reduction needed: each 16-lane group privately owns one vertex.

constexpr int VN  = 100000;
constexpr int KN  = 32;
constexpr int FN  = 64;
constexpr int WPB = 4;               // waves per block
constexpr int TPW = 8;               // vertices per wave
constexpr int VPB = WPB * TPW;       // 32 vertices per block -> 3125 blocks exact

__device__ float g_scratch[(size_t)VN * FN];   // 25.6 MB fallback if ws too small

template <bool FIRST, bool BIAS>
__global__ __launch_bounds__(256, 8)
void gather_agg(const float* __restrict__ src,    // [VN][64] compact, 256B rows
                const int*   __restrict__ nbidx,  // [VN][32] int32
                const float* __restrict__ distsq, // [VN][32] f32
                const float* __restrict__ bias,   // [64] (BIAS only)
                float*       __restrict__ out,    // [VN][128]
                int out_col)
{
    const int lane = threadIdx.x & 63;
    const int wid  = threadIdx.x >> 6;
    const int tq   = lane >> 4;        // vertex within quad (0..3)
    const int fq   = lane & 15;        // float4 index within feature row

    // 8 vertices x 34 (w, byte-offset) pairs (2 pad pairs -> stride 68 floats
    // = 272B: keeps reads 16B-aligned and tq-groups on distinct banks)
    __shared__ float s_wo[WPB][TPW * 68];

    const int vbase = (blockIdx.x * WPB + wid) * TPW;

    // ---- stage all 256 (w, offset) pairs for this wave's 8 vertices ----
    {
        float4 d4 = ((const float4*)(distsq + (size_t)vbase * KN))[lane];
        int4   i4 = ((const int4*)  (nbidx  + (size_t)vbase * KN))[lane];
        const int s = 4 * lane;                       // first flat k-slot
        float* dst = s_wo[wid] + (s >> 5) * 68 + (s & 31) * 2;
        float4 lo, hi;
        lo.x = __expf(-10.0f * d4.x); lo.y = __int_as_float(i4.x * (FN * 4));
        lo.z = __expf(-10.0f * d4.y); lo.w = __int_as_float(i4.y * (FN * 4));
        hi.x = __expf(-10.0f * d4.z); hi.y = __int_as_float(i4.z * (FN * 4));
        hi.z = __expf(-10.0f * d4.w); hi.w = __int_as_float(i4.w * (FN * 4));
        ((float4*)dst)[0] = lo;
        ((float4*)dst)[1] = hi;
        // same-wave DS in-order: reads below see these writes (no barrier needed)
    }

    const float invK = 1.0f / KN;
    float4 b4 = {0, 0, 0, 0};
    if (BIAS) b4 = ((const float4*)bias)[fq];
    const char* sb = (const char*)src + (size_t)fq * 16;

#pragma unroll
    for (int g = 0; g < 2; ++g) {
        const int vl = g * 4 + tq;                    // vertex slot in wave
        const int vt = vbase + vl;
        const float* wo = s_wo[wid] + vl * 68;

        float4 a0 = {0, 0, 0, 0}, a1 = {0, 0, 0, 0};
        float  ws0 = 0.0f, ws1 = 0.0f;
#pragma unroll
        for (int k = 0; k < KN; k += 2) {
            float4 p = *(const float4*)(wo + 2 * k);  // {w_k, o_k, w_k1, o_k1}
            float4 x0 = *(const float4*)(sb + __float_as_int(p.y));
            float4 x1 = *(const float4*)(sb + __float_as_int(p.w));
            a0.x += p.x * x0.x; a0.y += p.x * x0.y;
            a0.z += p.x * x0.z; a0.w += p.x * x0.w;
            a1.x += p.z * x1.x; a1.y += p.z * x1.y;
            a1.z += p.z * x1.z; a1.w += p.z * x1.w;
            if (FIRST) { ws0 += p.x; ws1 += p.z; }
        }
        float4 acc;
        acc.x = a0.x + a1.x; acc.y = a0.y + a1.y;
        acc.z = a0.z + a1.z; acc.w = a0.w + a1.w;

        if (FIRST) {
            // translation invariance: acc -= y0_v * sum_k w_k
            const float wsum = ws0 + ws1;
            float4 self = *(const float4*)((const char*)src + (size_t)vt * (FN * 4) + fq * 16);
            acc.x -= self.x * wsum; acc.y -= self.y * wsum;
            acc.z -= self.z * wsum; acc.w -= self.w * wsum;
        }

        float4 h;
        h.x = acc.x * invK; h.y = acc.y * invK;
        h.z = acc.z * invK; h.w = acc.w * invK;
        if (BIAS) { h.x += b4.x; h.y += b4.y; h.z += b4.z; h.w += b4.w; }
        h.x = (h.x > 0.0f) ? h.x : __expf(h.x) - 1.0f;
        h.y = (h.y > 0.0f) ? h.y : __expf(h.y) - 1.0f;
        h.z = (h.z > 0.0f) ? h.z : __expf(h.z) - 1.0f;
        h.w = (h.w > 0.0f) ? h.w : __expf(h.w) - 1.0f;

        *(float4*)(out + (size_t)vt * 128 + out_col + fq * 4) = h;
    }
}

// dst[v][j] = sum_f src[v][f] * W[f][j]   (64x64, no bias, no activation)
__global__ __launch_bounds__(256, 4)
void matmul64(const float* __restrict__ src, int sstride,   // floats per row
              const float* __restrict__ W,                  // [64][64]
              float*       __restrict__ dst, int dstride)
{
    const int lane = threadIdx.x & 63;
    const int wid  = threadIdx.x >> 6;
    const int tq   = lane >> 4;
    const int fq   = lane & 15;

    __shared__ float s_x[WPB][TPW * 68];   // 8 rows x 64 (+4 pad)

    float wreg[FN];                        // lane j holds W[:,j]
#pragma unroll
    for (int f = 0; f < FN; ++f) wreg[f] = W[f * FN + lane];

    const int vbase = (blockIdx.x * WPB + wid) * TPW;

#pragma unroll
    for (int i = 0; i < 2; ++i) {
        const int r = i * 4 + tq;
        float4 xv = *(const float4*)(src + (size_t)(vbase + r) * sstride + fq * 4);
        *(float4*)(s_x[wid] + r * 68 + fq * 4) = xv;
    }
    // same-wave DS in-order; per-wave private slice -> no barrier

#pragma unroll
    for (int r = 0; r < TPW; ++r) {
        const float* xr = s_x[wid] + r * 68;
        float hacc[4] = {0, 0, 0, 0};
#pragma unroll
        for (int f4 = 0; f4 < 16; ++f4) {
            float4 a = *(const float4*)(xr + f4 * 4);   // uniform-addr broadcast
            hacc[f4 & 3] += a.x * wreg[f4 * 4 + 0] + a.y * wreg[f4 * 4 + 1]
                          + a.z * wreg[f4 * 4 + 2] + a.w * wreg[f4 * 4 + 3];
        }
        const float h = (hacc[0] + hacc[1]) + (hacc[2] + hacc[3]);
        dst[(size_t)(vbase + r) * dstride + lane] = h;
    }
}

extern "C" void kernel_launch(void* const* d_in, const int* in_sizes, int n_in,
                              void* d_out, int out_size, void* d_ws, size_t ws_size,
                              hipStream_t stream) {
    const float* x   = (const float*)d_in[0];
    const int*   nb  = (const int*)  d_in[1];
    const float* dsq = (const float*)d_in[2];
    const float* W0  = (const float*)d_in[3];
    const float* W1  = (const float*)d_in[4];
    const float* b1  = (const float*)d_in[5];
    float* out = (float*)d_out;

    const size_t need = (size_t)VN * FN * sizeof(float);
    float* ws = (ws_size >= need) ? (float*)d_ws : g_scratch;

    const int blocks = VN / VPB;   // 3125 exact

    // A: y0 = x @ W0 -> ws
    matmul64<<<blocks, 256, 0, stream>>>(x, FN, W0, ws, FN);
    // B: h0 = elu(TI-agg(y0)) -> out[:, 0:64]
    gather_agg<true, false><<<blocks, 256, 0, stream>>>(ws, nb, dsq, nullptr, out, 0);
    // C: z = h0 @ W1 -> ws   (h0 rows live at out[v][0:64], stride 128)
    matmul64<<<blocks, 256, 0, stream>>>(out, 2 * FN, W1, ws, FN);
    // D: h1 = elu(agg(z) + b1) -> out[:, 64:128]
    gather_agg<false, true><<<blocks, 256, 0, stream>>>(ws, nb, dsq, b1, out, 64);
}